// Round 12
// baseline (486.626 us; speedup 1.0000x reference)
//
#include <hip/hip_runtime.h>
#include <hip/hip_bf16.h>
#include <hip/hip_cooperative_groups.h>
#include <math.h>

namespace cg = cooperative_groups;

#define Bn 4096
#define Dd 768
#define SC2 28.85390081777927f   // 20 * log2(e): logits kept in base-2 domain
#define EPSF 1e-6f
#define DG 4.8516519541e8f       // expf(20.0f): exact exp_ori diagonal

// ws layout (4-byte elements)
#define O_S      0        // 3*4096 row sums (ori_nodiag, gen, aug)
#define O_SMOA   12288    // same-masked (ori_nodiag + aug) sums
#define O_SMG    16384    // same-masked gen sums
#define ZERO_F   20480    // floats to zero (covers all atomic sums)
#define O_P      20480    // uint: total pairs (= sum cnt^2)
#define O_RM     20608    // uint2[4096]: {tg | rank<<8, rowSlotBase}
#define LIST_OFF   262144      // byte offset: LCAP uint4 pair entries {row,x0,x1,x2}
#define LCAP       (1u << 19)
#define NB_OFF     33554432    // byte offset: bf16 normalized rows on|gn|an

typedef __attribute__((ext_vector_type(8))) short sh8;
typedef __attribute__((ext_vector_type(4))) float f32x4;

#define AS1 __attribute__((address_space(1)))
#define AS3 __attribute__((address_space(3)))

static __device__ __forceinline__ void gl_lds16(const void* g, void* l) {
    __builtin_amdgcn_global_load_lds((const AS1 void*)g, (AS3 void*)l, 16, 0, 0);
}

static __device__ __forceinline__ unsigned short f2b(float f) {
    unsigned int u = __float_as_uint(f);
    unsigned int r = (u + 0x7fffu + ((u >> 16) & 1u)) >> 16;  // RNE
    return (unsigned short)r;
}

// One cooperative kernel, G x 512 threads (G from occupancy query; all loops
// grid-stride so any G is correct; G in {256, 512} divides the 1024 tiles).
// R11 lesson: requesting 1024x256 with 4 blocks/CU assumed ~80 regs, but the
// unified VGPR+AGPR file holds 64 acc + ~80 working = ~144 -> 3 blocks/CU ->
// cooperative launch REJECTED (out stayed zero). Fix: 8-wave blocks cut acc
// to 32 regs/thread (each wave: 64x32 subtile, acc[4][2]) so the 128-reg cap
// from __launch_bounds__(512,4) fits ~2 blocks/CU = 16 waves/CU.
// Phase 1: block 0 zeroes sums + class-sorts; other blocks normalize rows.
// Phase 2: GEMM per tile-triple (z=0,1,2 at fixed m0,n0; A L2-warm across z).
//   K-loop = R9's measured best: BK=32, swizzle pos=seg^((row>>1)&3)
//   (0 conflicts R4-R10), deterministic pair slots rsb[i]+rank[j],
//   fire-and-forget stores, NO returning atomics (R4: 4.3ms; R5: +130us).
// Phase 3: flat loss over pair list, inline denominators, atomics to d_out.
__global__ __launch_bounds__(512, 4) void mega_kernel(
        const float* f0, const float* f1, const float* f2, const int* tg,
        unsigned short* nb, char* ws, float* out) {
    cg::grid_group grid = cg::this_grid();
    __shared__ __align__(16) char smem[16384];
    float* F = (float*)ws;
    unsigned int* I = (unsigned int*)ws;
    int b = blockIdx.x, tid = threadIdx.x, G = gridDim.x;
    int lane = tid & 63, wave = tid >> 6;

    // ---- phase 1 ----
    if (b == 0) {
        for (int e = tid; e < ZERO_F; e += 512) F[e] = 0.f;
        if (tid == 0) { out[0] = 0.f; out[1] = 0.f; }
        unsigned int* h = (unsigned int*)smem;
        unsigned int* pb = h + 128;
        unsigned int* cur = h + 256;
        if (tid < 128) { h[tid] = 0; cur[tid] = 0; }
        __syncthreads();
        for (int e = tid; e < Bn; e += 512) atomicAdd(&h[tg[e]], 1u);
        __syncthreads();
        if (tid < 128) pb[tid] = h[tid] * h[tid];
        __syncthreads();
        for (int s = 1; s < 128; s <<= 1) {
            unsigned int v = 0;
            if (tid < 128 && tid >= s) v = pb[tid - s];
            __syncthreads();
            if (tid < 128) pb[tid] += v;
            __syncthreads();
        }
        if (tid == 127) I[O_P] = pb[127];
        uint2* RMw = (uint2*)(I + O_RM);
        for (int e = tid; e < Bn; e += 512) {
            int c = tg[e];
            unsigned int r = atomicAdd(&cur[c], 1u);
            unsigned int n = h[c];
            RMw[e] = make_uint2((unsigned)c | (r << 8), (pb[c] - n * n) + r * n);
        }
    } else {
        float* wr = (float*)smem;
        for (int task = b - 1; task < 3 * Bn; task += G - 1) {
            int m = task >> 12, r = task & (Bn - 1);
            const float* src = (m == 0 ? f0 : (m == 1 ? f1 : f2)) + (size_t)r * Dd;
            float x0 = src[tid];
            float x1 = (tid < 256) ? src[tid + 512] : 0.f;
            float v = x0 * x0 + x1 * x1;
            #pragma unroll
            for (int off = 1; off < 64; off <<= 1) v += __shfl_xor(v, off);
            if (lane == 0) wr[wave] = v;
            __syncthreads();
            float inv = rsqrtf(wr[0] + wr[1] + wr[2] + wr[3] + wr[4] + wr[5] + wr[6] + wr[7]);
            unsigned short* dst = nb + ((size_t)m * Bn + r) * Dd;
            dst[tid] = f2b(x0 * inv);
            if (tid < 256) dst[tid + 512] = f2b(x1 * inv);
            __syncthreads();
        }
    }
    grid.sync();

    // ---- phase 2: gemm over tile-triples ----
    const uint2* RM = (const uint2*)(I + O_RM);
    unsigned short* Asm = (unsigned short*)smem;
    unsigned short* Bsm = Asm + 128 * 32;
    // 8 waves: wm = (wave>>2)*64 (2 row groups), wn = (wave&3)*32 (4 col groups)
    int wm = (wave >> 2) * 64, wn = (wave & 3) * 32;
    int lid = lane & 15, q = lane >> 4;
    // staging: one A-seg + one B-seg per thread (512 segs of 8 bf16 each)
    int srow = tid >> 2, spos = tid & 3;
    int sseg = spos ^ ((srow >> 1) & 3);
    unsigned int* Lw = (unsigned int*)(ws + LIST_OFF);
    for (int t = b; t < 1024; t += G) {
        int m0 = (t >> 5) * 128, n0 = (t & 31) * 128;
        uint2 rmc[2];
        #pragma unroll
        for (int j = 0; j < 2; ++j) rmc[j] = RM[n0 + wn + j * 16 + lid];
        const unsigned short* gA = nb + (size_t)(m0 + srow) * Dd + sseg * 8;
        for (int z = 0; z < 3; ++z) {
            const unsigned short* gB = nb + (size_t)z * Bn * Dd + (size_t)(n0 + srow) * Dd + sseg * 8;
            f32x4 acc[4][2] = {};
            for (int kt = 0; kt < Dd / 32; ++kt) {
                __syncthreads();
                gl_lds16(gA + kt * 32, &Asm[tid * 8]);
                gl_lds16(gB + kt * 32, &Bsm[tid * 8]);
                __syncthreads();
                sh8 af[4], bf[2];
                #pragma unroll
                for (int i = 0; i < 4; ++i) {
                    int r = wm + i * 16 + lid;
                    af[i] = *(const sh8*)&Asm[r * 32 + ((q ^ ((r >> 1) & 3)) * 8)];
                }
                #pragma unroll
                for (int j = 0; j < 2; ++j) {
                    int r = wn + j * 16 + lid;
                    bf[j] = *(const sh8*)&Bsm[r * 32 + ((q ^ ((r >> 1) & 3)) * 8)];
                }
                #pragma unroll
                for (int i = 0; i < 4; ++i)
                    #pragma unroll
                    for (int j = 0; j < 2; ++j)
                        acc[i][j] = __builtin_amdgcn_mfma_f32_16x16x32_bf16(af[i], bf[j], acc[i][j], 0, 0, 0);
            }
            // epilogue: row sum, masked sum, pair-list word stores
            int smoff = (z == 1) ? O_SMG : O_SMOA;
            #pragma unroll
            for (int i = 0; i < 4; ++i)
                #pragma unroll
                for (int reg = 0; reg < 4; ++reg) {
                    int grow = m0 + wm + i * 16 + q * 4 + reg;
                    uint2 rm = RM[grow];
                    unsigned int trow = rm.x & 255u, rsb = rm.y;
                    float rs = 0.f, ms = 0.f;
                    #pragma unroll
                    for (int j = 0; j < 2; ++j) {
                        int gcol = n0 + wn + j * 16 + lid;
                        float x = acc[i][j][reg] * SC2;
                        float e = exp2f(x);
                        if (z == 0 && gcol == grow) e = 0.f;
                        rs += e;
                        if ((rmc[j].x & 255u) == trow) {
                            ms += e;
                            unsigned int slot = rsb + (rmc[j].x >> 8);
                            if (slot < LCAP) {
                                if (z == 0) {
                                    Lw[slot * 4 + 0] = (unsigned)grow;
                                    Lw[slot * 4 + 1] = __float_as_uint(x);
                                } else {
                                    Lw[slot * 4 + 1 + z] = __float_as_uint(x);
                                }
                            }
                        }
                    }
                    #pragma unroll
                    for (int off = 1; off < 16; off <<= 1) {
                        rs += __shfl_xor(rs, off);
                        ms += __shfl_xor(ms, off);
                    }
                    if (lid == 0) {
                        atomicAdd(&F[O_S + z * Bn + grow], rs);
                        atomicAdd(&F[smoff + grow], ms);
                    }
                }
        }
    }
    grid.sync();

    // ---- phase 3: loss ----
    {
        const uint4* L = (const uint4*)(ws + LIST_OFF);
        unsigned int n = I[O_P]; if (n > LCAP) n = LCAP;
        float a0 = 0.f, a1 = 0.f;
        unsigned int stride = (unsigned int)G * 512u;
        for (unsigned int idx = b * 512 + tid; idx < n; idx += stride) {
            uint4 en = L[idx];
            int i = (int)en.x;
            float son = F[O_S + i], sgen = F[O_S + Bn + i], saug = F[O_S + 2 * Bn + i];
            float dco = (son + saug - F[O_SMOA + i]) + sgen + EPSF;
            float dad = (sgen - F[O_SMG + i]) + saug + son + DG + EPSF;
            float eo = exp2f(__uint_as_float(en.y));
            float eg = exp2f(__uint_as_float(en.z));
            float ea = exp2f(__uint_as_float(en.w));
            a0 += -__logf(eg / (eg + dad) + EPSF);
            a1 += -__logf(eo / (eo + dco) + EPSF) - __logf(ea / (ea + dco) + EPSF);
        }
        #pragma unroll
        for (int off = 1; off < 64; off <<= 1) { a0 += __shfl_xor(a0, off); a1 += __shfl_xor(a1, off); }
        float* r0 = (float*)smem;
        float* r1 = r0 + 8;
        __syncthreads();
        if (lane == 0) { r0[wave] = a0; r1[wave] = a1; }
        __syncthreads();
        if (tid == 0) {
            float s0 = r0[0] + r0[1] + r0[2] + r0[3] + r0[4] + r0[5] + r0[6] + r0[7];
            float s1 = r1[0] + r1[1] + r1[2] + r1[3] + r1[4] + r1[5] + r1[6] + r1[7];
            atomicAdd(&out[0], s0 * (1.0f / Bn));  // ad_loss
            atomicAdd(&out[1], s1 * (1.0f / Bn));  // co_loss
        }
    }
}

extern "C" void kernel_launch(void* const* d_in, const int* in_sizes, int n_in,
                              void* d_out, int out_size, void* d_ws, size_t ws_size,
                              hipStream_t stream) {
    const float* f0 = (const float*)d_in[0];
    const float* f1 = (const float*)d_in[1];
    const float* f2 = (const float*)d_in[2];
    const int* tg = (const int*)d_in[3];
    char* ws = (char*)d_ws;
    unsigned short* nb = (unsigned short*)(ws + NB_OFF);
    float* out = (float*)d_out;

    // Occupancy-derived grid (query only -- graph-capture safe). All device
    // loops are grid-stride; G in {256,512} divides the 1024 tiles evenly.
    int occ = 0;
    (void)hipOccupancyMaxActiveBlocksPerMultiprocessor(&occ, (const void*)mega_kernel, 512, 0);
    int G = (occ >= 2) ? 512 : 256;

    void* args[] = { (void*)&f0, (void*)&f1, (void*)&f2, (void*)&tg,
                     (void*)&nb, (void*)&ws, (void*)&out };
    hipLaunchCooperativeKernel((const void*)mega_kernel, dim3(G), dim3(512),
                               args, 0, stream);
}

// Round 13
// 312.607 us; speedup vs baseline: 1.5567x; 1.5567x over previous
//
#include <hip/hip_runtime.h>
#include <hip/hip_bf16.h>
#include <math.h>

#define Bn 4096
#define Dd 768
#define SC2 28.85390081777927f   // 20 * log2(e): logits kept in base-2 domain
#define EPSF 1e-6f
#define DG 4.8516519541e8f       // expf(20.0f): exact exp_ori diagonal

// ws layout (4-byte elements)
#define O_S      0        // 3*4096 row sums (ori_nodiag, gen, aug)
#define O_SMOA   12288    // same-masked (ori_nodiag + aug) sums
#define O_SMG    16384    // same-masked gen sums
#define ZERO_F   20480    // floats to zero (covers all atomic sums)
#define O_P      20480    // uint: total pairs (= sum cnt^2)
#define O_RM     20608    // uint2[4096]: {tg | rank<<8, rowSlotBase}
#define LIST_OFF   262144      // byte offset: LCAP uint4 pair entries {row,x0,x1,x2}
#define LCAP       (1u << 19)
#define NB_OFF     33554432    // byte offset: fp8 e4m3 normalized rows on|gn|an

typedef __attribute__((ext_vector_type(4))) float f32x4;
typedef __attribute__((ext_vector_type(8))) int i32x8;

#define AS1 __attribute__((address_space(1)))
#define AS3 __attribute__((address_space(3)))

static __device__ __forceinline__ void gl_lds16(const void* g, void* l) {
    __builtin_amdgcn_global_load_lds((const AS1 void*)g, (AS3 void*)l, 16, 0, 0);
}

// exact RNE float -> OCP e4m3fn (valid for |f| <= 1, finite)
static __device__ __forceinline__ unsigned int f2e4m3(float f) {
    unsigned int u = __float_as_uint(f);
    unsigned int sign = (u >> 24) & 0x80u;
    int exp = (int)((u >> 23) & 0xffu) - 127;
    unsigned int man = u & 0x7fffffu;
    if (exp >= -6) {                      // normal in e4m3 (|f|<=1 -> no overflow)
        unsigned int mant = man >> 20;
        unsigned int rest = man & 0xfffffu;
        unsigned int v = ((unsigned int)(exp + 7) << 3) | mant;
        if (rest > 0x80000u || (rest == 0x80000u && (v & 1u))) v++;
        return sign | v;
    }
    if (exp <= -11) return sign;          // rounds to zero
    int rs = 20 + (-6 - exp);             // 21..24
    unsigned int full = 0x800000u | man;
    unsigned int mant = full >> rs;
    unsigned int rest = full & ((1u << rs) - 1u);
    unsigned int half = 1u << (rs - 1);
    if (rest > half || (rest == half && (mant & 1u))) mant++;
    return sign | mant;                   // mant==8 -> 0x08 == 2^-6, correct
}

// ---- normalize rows, write fp8 e4m3 (192 lanes x float4 per row) ----
__global__ void norm_kernel(const float* f0, const float* f1, const float* f2, unsigned char* nb) {
    int r = blockIdx.x, m = blockIdx.y, tid = threadIdx.x;
    const float* src = (m == 0 ? f0 : (m == 1 ? f1 : f2)) + (size_t)r * Dd;
    float4 x = make_float4(0.f, 0.f, 0.f, 0.f);
    if (tid < 192) x = ((const float4*)src)[tid];
    float v = x.x * x.x + x.y * x.y + x.z * x.z + x.w * x.w;
    #pragma unroll
    for (int off = 1; off < 64; off <<= 1) v += __shfl_xor(v, off);
    __shared__ float wr[4];
    if ((tid & 63) == 0) wr[tid >> 6] = v;
    __syncthreads();
    float inv = rsqrtf(wr[0] + wr[1] + wr[2] + wr[3]);
    if (tid < 192) {
        unsigned int p = f2e4m3(x.x * inv) | (f2e4m3(x.y * inv) << 8) |
                         (f2e4m3(x.z * inv) << 16) | (f2e4m3(x.w * inv) << 24);
        ((unsigned int*)(nb + ((size_t)m * Bn + r) * Dd))[tid] = p;
    }
}

// ---- single-block class sort: zero sums + hist/scan/rank+slot ----
__launch_bounds__(1024)
__global__ void sort_kernel(const int* tg, unsigned int* I, float* out) {
    float* F = (float*)I;
    __shared__ unsigned int h[128], pb[128], cur[128];
    int tid = threadIdx.x;
    for (int e = tid; e < ZERO_F; e += 1024) F[e] = 0.f;
    if (tid == 0) { out[0] = 0.f; out[1] = 0.f; }
    if (tid < 128) { h[tid] = 0; cur[tid] = 0; }
    __syncthreads();
    for (int e = tid; e < Bn; e += 1024) atomicAdd(&h[tg[e]], 1u);
    __syncthreads();
    if (tid < 128) pb[tid] = h[tid] * h[tid];
    __syncthreads();
    for (int s = 1; s < 128; s <<= 1) {
        unsigned int b = 0;
        if (tid < 128 && tid >= s) b = pb[tid - s];
        __syncthreads();
        if (tid < 128) pb[tid] += b;
        __syncthreads();
    }
    if (tid == 127) I[O_P] = pb[127];
    uint2* RM = (uint2*)(I + O_RM);
    for (int e = tid; e < Bn; e += 1024) {
        int c = tg[e];
        unsigned int r = atomicAdd(&cur[c], 1u);
        unsigned int n = h[c];
        RM[e] = make_uint2((unsigned)c | (r << 8), (pb[c] - n * n) + r * n);
    }
}

// ---- fused fp8-MX GEMM + exp row-sum + masked sums + pair extraction.
// z selects B-operand (0:on 1:gn 2:an); A always on. mfma_scale 16x16x128
// fp8 with unit scales (0x7f = 1.0): K-iters 24 -> 6 (4x fewer barrier
// pairs -- R9's K-loop was 60% barrier-idle), staged bytes halved.
// LDS 128x128B tiles, 16B slot swizzle pos = slot ^ (row&7): each b128
// phase spreads over 8 4-bank groups (0 conflicts R4-R10 with same scheme).
// Pair slots deterministic (rsb[i]+rank[j]) -> fire-and-forget stores, NO
// returning atomics (R4: 4.3ms; R5: +130us). acc stays 64 regs (R7 lesson);
// B-frag loaded per-j to cap VGPR pressure.
__launch_bounds__(256)
__global__ void gemm_rowsum(const unsigned char* nb, char* ws) {
    float* F = (float*)ws;
    const unsigned int* I = (const unsigned int*)ws;
    const uint2* RM = (const uint2*)(I + O_RM);
    int z = blockIdx.z;
    const unsigned char* Ag = nb;
    const unsigned char* Bg = nb + (size_t)z * Bn * Dd;
    int m0 = blockIdx.y * 128, n0 = blockIdx.x * 128;
    int tid = threadIdx.x, lane = tid & 63, wave = tid >> 6;
    int wm = (wave >> 1) * 64, wn = (wave & 1) * 64;
    int lid = lane & 15, q = lane >> 4;
    __shared__ __align__(16) unsigned char Asm[128 * 128];
    __shared__ __align__(16) unsigned char Bsm[128 * 128];
    // staging: 1024 16B-chunks per matrix; chunk c -> row c>>3, slot c&7
    // holding global 16B-seg (c&7)^(row&7). 4 chunks/thread/matrix.
    int crow[4], cgs[4];
    #pragma unroll
    for (int s = 0; s < 4; ++s) {
        int c = tid + s * 256;
        crow[s] = c >> 3;
        cgs[s] = (c & 7) ^ (crow[s] & 7);
    }
    f32x4 acc[4][4] = {};
    for (int kt = 0; kt < Dd / 128; ++kt) {
        __syncthreads();
        #pragma unroll
        for (int s = 0; s < 4; ++s) {
            int c = tid + s * 256;
            gl_lds16(Ag + (size_t)(m0 + crow[s]) * Dd + kt * 128 + cgs[s] * 16, &Asm[c * 16]);
            gl_lds16(Bg + (size_t)(n0 + crow[s]) * Dd + kt * 128 + cgs[s] * 16, &Bsm[c * 16]);
        }
        __syncthreads();
        i32x8 af[4];
        #pragma unroll
        for (int i = 0; i < 4; ++i) {
            int r = wm + i * 16 + lid;
            int4 lo = *(const int4*)&Asm[r * 128 + (((q * 2 + 0) ^ (r & 7)) * 16)];
            int4 hi = *(const int4*)&Asm[r * 128 + (((q * 2 + 1) ^ (r & 7)) * 16)];
            af[i] = (i32x8){lo.x, lo.y, lo.z, lo.w, hi.x, hi.y, hi.z, hi.w};
        }
        #pragma unroll
        for (int j = 0; j < 4; ++j) {
            int r = wn + j * 16 + lid;
            int4 lo = *(const int4*)&Bsm[r * 128 + (((q * 2 + 0) ^ (r & 7)) * 16)];
            int4 hi = *(const int4*)&Bsm[r * 128 + (((q * 2 + 1) ^ (r & 7)) * 16)];
            i32x8 bf = (i32x8){lo.x, lo.y, lo.z, lo.w, hi.x, hi.y, hi.z, hi.w};
            #pragma unroll
            for (int i = 0; i < 4; ++i)
                acc[i][j] = __builtin_amdgcn_mfma_scale_f32_16x16x128_f8f6f4(
                    af[i], bf, acc[i][j], 0, 0, 0, 0x7f7f7f7f, 0, 0x7f7f7f7f);
        }
    }
    // ---- epilogue: row sum, masked sum, pair-list word stores ----
    uint2 rmc[4];
    #pragma unroll
    for (int j = 0; j < 4; ++j) rmc[j] = RM[n0 + wn + j * 16 + lid];
    int smoff = (z == 1) ? O_SMG : O_SMOA;
    unsigned int* Lw = (unsigned int*)(ws + LIST_OFF);
    #pragma unroll
    for (int i = 0; i < 4; ++i)
        #pragma unroll
        for (int reg = 0; reg < 4; ++reg) {
            int grow = m0 + wm + i * 16 + q * 4 + reg;
            uint2 rm = RM[grow];
            unsigned int trow = rm.x & 255u, rsb = rm.y;
            float rs = 0.f, ms = 0.f;
            #pragma unroll
            for (int j = 0; j < 4; ++j) {
                int gcol = n0 + wn + j * 16 + lid;
                float x = acc[i][j][reg] * SC2;
                float e = exp2f(x);
                if (z == 0 && gcol == grow) e = 0.f;
                rs += e;
                if ((rmc[j].x & 255u) == trow) {
                    ms += e;
                    unsigned int slot = rsb + (rmc[j].x >> 8);
                    if (slot < LCAP) {
                        if (z == 0) {
                            Lw[slot * 4 + 0] = (unsigned)grow;
                            Lw[slot * 4 + 1] = __float_as_uint(x);
                        } else {
                            Lw[slot * 4 + 1 + z] = __float_as_uint(x);
                        }
                    }
                }
            }
            #pragma unroll
            for (int off = 1; off < 16; off <<= 1) {
                rs += __shfl_xor(rs, off);
                ms += __shfl_xor(ms, off);
            }
            if (lid == 0) {
                atomicAdd(&F[O_S + z * Bn + grow], rs);
                atomicAdd(&F[smoff + grow], ms);
            }
        }
}

// ---- flat loss pass: inline denominators, scaled atomic into d_out ----
__launch_bounds__(256)
__global__ void loss_kernel(char* ws, float* out) {
    float* F = (float*)ws;
    const unsigned int* I = (const unsigned int*)ws;
    const uint4* L = (const uint4*)(ws + LIST_OFF);
    unsigned int n = I[O_P]; if (n > LCAP) n = LCAP;
    float a0 = 0.f, a1 = 0.f;
    unsigned int stride = gridDim.x * 256;
    for (unsigned int idx = blockIdx.x * 256 + threadIdx.x; idx < n; idx += stride) {
        uint4 en = L[idx];
        int i = (int)en.x;
        float son = F[O_S + i], sgen = F[O_S + Bn + i], saug = F[O_S + 2 * Bn + i];
        float dco = (son + saug - F[O_SMOA + i]) + sgen + EPSF;
        float dad = (sgen - F[O_SMG + i]) + saug + son + DG + EPSF;
        float eo = exp2f(__uint_as_float(en.y));
        float eg = exp2f(__uint_as_float(en.z));
        float ea = exp2f(__uint_as_float(en.w));
        a0 += -__logf(eg / (eg + dad) + EPSF);
        a1 += -__logf(eo / (eo + dco) + EPSF) - __logf(ea / (ea + dco) + EPSF);
    }
    #pragma unroll
    for (int off = 1; off < 64; off <<= 1) { a0 += __shfl_xor(a0, off); a1 += __shfl_xor(a1, off); }
    __shared__ float r0[4], r1[4];
    int tid = threadIdx.x;
    if ((tid & 63) == 0) { r0[tid >> 6] = a0; r1[tid >> 6] = a1; }
    __syncthreads();
    if (tid == 0) {
        atomicAdd(&out[0], (r0[0] + r0[1] + r0[2] + r0[3]) * (1.0f / Bn));  // ad_loss
        atomicAdd(&out[1], (r1[0] + r1[1] + r1[2] + r1[3]) * (1.0f / Bn));  // co_loss
    }
}

extern "C" void kernel_launch(void* const* d_in, const int* in_sizes, int n_in,
                              void* d_out, int out_size, void* d_ws, size_t ws_size,
                              hipStream_t stream) {
    const float* f0 = (const float*)d_in[0];
    const float* f1 = (const float*)d_in[1];
    const float* f2 = (const float*)d_in[2];
    const int* tg = (const int*)d_in[3];
    char* ws = (char*)d_ws;
    unsigned int* I = (unsigned int*)d_ws;
    unsigned char* nb = (unsigned char*)(ws + NB_OFF);
    float* out = (float*)d_out;

    norm_kernel<<<dim3(Bn, 3), 256, 0, stream>>>(f0, f1, f2, nb);
    sort_kernel<<<1, 1024, 0, stream>>>(tg, I, out);
    gemm_rowsum<<<dim3(32, 32, 3), 256, 0, stream>>>(nb, ws);
    loss_kernel<<<256, 256, 0, stream>>>(ws, out);
}

// Round 14
// 220.649 us; speedup vs baseline: 2.2054x; 1.4168x over previous
//
#include <hip/hip_runtime.h>
#include <hip/hip_bf16.h>
#include <math.h>

#define Bn 4096
#define Dd 768
#define SC2 28.85390081777927f   // 20 * log2(e): logits kept in base-2 domain
#define EPSF 1e-6f
#define DG 4.8516519541e8f       // expf(20.0f): exact exp_ori diagonal

// ws layout (4-byte elements)
#define O_S      0        // 3*4096 row sums (ori_nodiag, gen, aug)
#define O_SMOA   12288    // same-masked (ori_nodiag + aug) sums
#define O_SMG    16384    // same-masked gen sums
#define ZERO_F   20480    // floats to zero (covers all atomic sums)
#define O_P      20480    // uint: total pairs (= sum cnt^2)
#define O_RM     20608    // uint2[4096]: {tg | rank<<8, rowSlotBase}
#define LIST_OFF   262144      // byte offset: LCAP uint4 pair entries {row,x0,x1,x2}
#define LCAP       (1u << 19)
#define NB_OFF     33554432    // byte offset: bf16 normalized rows on|gn|an

typedef __attribute__((ext_vector_type(8))) short sh8;
typedef __attribute__((ext_vector_type(4))) float f32x4;

#define AS1 __attribute__((address_space(1)))
#define AS3 __attribute__((address_space(3)))

static __device__ __forceinline__ void gl_lds16(const void* g, void* l) {
    __builtin_amdgcn_global_load_lds((const AS1 void*)g, (AS3 void*)l, 16, 0, 0);
}

static __device__ __forceinline__ unsigned short f2b(float f) {
    unsigned int u = __float_as_uint(f);
    unsigned int r = (u + 0x7fffu + ((u >> 16) & 1u)) >> 16;  // RNE
    return (unsigned short)r;
}

// ---- normalize rows, write bf16 ----
__global__ void norm_kernel(const float* f0, const float* f1, const float* f2, unsigned short* nb) {
    int r = blockIdx.x, m = blockIdx.y, tid = threadIdx.x;
    const float* src = (m == 0 ? f0 : (m == 1 ? f1 : f2)) + (size_t)r * Dd;
    float x0 = src[tid], x1 = src[tid + 256], x2 = src[tid + 512];
    float v = x0 * x0 + x1 * x1 + x2 * x2;
    #pragma unroll
    for (int off = 1; off < 64; off <<= 1) v += __shfl_xor(v, off);
    __shared__ float wr[4];
    if ((tid & 63) == 0) wr[tid >> 6] = v;
    __syncthreads();
    float inv = rsqrtf(wr[0] + wr[1] + wr[2] + wr[3]);
    unsigned short* dst = nb + ((size_t)m * Bn + r) * Dd;
    dst[tid] = f2b(x0 * inv);
    dst[tid + 256] = f2b(x1 * inv);
    dst[tid + 512] = f2b(x2 * inv);
}

// ---- single-block: zero accumulators + class sort (hist/scan/rank+slot) ----
__launch_bounds__(1024)
__global__ void sort_kernel(const int* tg, unsigned int* I, float* out) {
    float* F = (float*)I;
    __shared__ unsigned int h[128], pb[128], cur[128];
    int tid = threadIdx.x;
    for (int e = tid; e < ZERO_F; e += 1024) F[e] = 0.f;
    if (tid == 0) { out[0] = 0.f; out[1] = 0.f; }
    if (tid < 128) { h[tid] = 0; cur[tid] = 0; }
    __syncthreads();
    for (int e = tid; e < Bn; e += 1024) atomicAdd(&h[tg[e]], 1u);
    __syncthreads();
    if (tid < 128) pb[tid] = h[tid] * h[tid];
    __syncthreads();
    for (int s = 1; s < 128; s <<= 1) {
        unsigned int b = 0;
        if (tid < 128 && tid >= s) b = pb[tid - s];
        __syncthreads();
        if (tid < 128) pb[tid] += b;
        __syncthreads();
    }
    if (tid == 127) I[O_P] = pb[127];
    uint2* RM = (uint2*)(I + O_RM);
    for (int e = tid; e < Bn; e += 1024) {
        int c = tg[e];
        unsigned int r = atomicAdd(&cur[c], 1u);
        unsigned int n = h[c];
        RM[e] = make_uint2((unsigned)c | (r << 8), (pb[c] - n * n) + r * n);
    }
}

// ---- fused GEMM + exp row-sum + masked sums + deterministic pair extraction.
// R9's measured-best structure (BK=32, 128x128, conflict-free swizzle
// pos=seg^((row>>1)&3), deterministic fire-and-forget pair slots, no
// returning atomics) with ONE change: __launch_bounds__(256,4) caps the
// unified VGPR+AGPR budget at 128 -> 4 waves/EU (R9 floated at ~144 regs ->
// 2.6 blocks/CU, 33% occupancy, 60% barrier-idle). Epilogue-only values may
// spill to scratch (once per block) -- acceptable if the K-loop stays clean.
// (R7 acc-fusion, R8 BK=64, R10 symmetry, R12 coop, R13 fp8-MX all lost to
// occupancy collapse; this attacks occupancy directly.)
__launch_bounds__(256, 4)
__global__ void gemm_rowsum(const unsigned short* nb, char* ws) {
    float* F = (float*)ws;
    const unsigned int* I = (const unsigned int*)ws;
    const uint2* RM = (const uint2*)(I + O_RM);
    int z = blockIdx.z;
    const unsigned short* Ag = nb;
    const unsigned short* Bg = nb + (size_t)z * Bn * Dd;
    int m0 = blockIdx.y * 128, n0 = blockIdx.x * 128;
    int tid = threadIdx.x, lane = tid & 63, wave = tid >> 6;
    int wm = (wave >> 1) * 64, wn = (wave & 1) * 64;
    int lid = lane & 15, q = lane >> 4;
    __shared__ __align__(16) unsigned short Asm[128 * 32];
    __shared__ __align__(16) unsigned short Bsm[128 * 32];
    int c0 = tid, c1 = tid + 256;
    int row0 = c0 >> 2, sg0 = (c0 & 3) ^ ((row0 >> 1) & 3);
    int row1 = c1 >> 2, sg1 = (c1 & 3) ^ ((row1 >> 1) & 3);
    const unsigned short* gA0 = Ag + (size_t)(m0 + row0) * Dd + sg0 * 8;
    const unsigned short* gA1 = Ag + (size_t)(m0 + row1) * Dd + sg1 * 8;
    const unsigned short* gB0 = Bg + (size_t)(n0 + row0) * Dd + sg0 * 8;
    const unsigned short* gB1 = Bg + (size_t)(n0 + row1) * Dd + sg1 * 8;
    unsigned short* lA0 = &Asm[c0 * 8];
    unsigned short* lA1 = &Asm[c1 * 8];
    unsigned short* lB0 = &Bsm[c0 * 8];
    unsigned short* lB1 = &Bsm[c1 * 8];
    f32x4 acc[4][4] = {};
    for (int kt = 0; kt < Dd / 32; ++kt) {
        __syncthreads();
        gl_lds16(gA0 + kt * 32, lA0);
        gl_lds16(gA1 + kt * 32, lA1);
        gl_lds16(gB0 + kt * 32, lB0);
        gl_lds16(gB1 + kt * 32, lB1);
        __syncthreads();
        sh8 af[4], bf[4];
        #pragma unroll
        for (int i = 0; i < 4; ++i) {
            int r = wm + i * 16 + lid;
            af[i] = *(const sh8*)&Asm[r * 32 + ((q ^ ((r >> 1) & 3)) * 8)];
        }
        #pragma unroll
        for (int j = 0; j < 4; ++j) {
            int r = wn + j * 16 + lid;
            bf[j] = *(const sh8*)&Bsm[r * 32 + ((q ^ ((r >> 1) & 3)) * 8)];
        }
        #pragma unroll
        for (int i = 0; i < 4; ++i)
            #pragma unroll
            for (int j = 0; j < 4; ++j)
                acc[i][j] = __builtin_amdgcn_mfma_f32_16x16x32_bf16(af[i], bf[j], acc[i][j], 0, 0, 0);
    }
    // ---- epilogue: row sum, masked sum, pair-list word stores ----
    uint2 rmc[4];
    #pragma unroll
    for (int j = 0; j < 4; ++j) rmc[j] = RM[n0 + wn + j * 16 + lid];
    int smoff = (z == 1) ? O_SMG : O_SMOA;
    unsigned int* Lw = (unsigned int*)(ws + LIST_OFF);
    #pragma unroll
    for (int i = 0; i < 4; ++i)
        #pragma unroll
        for (int reg = 0; reg < 4; ++reg) {
            int grow = m0 + wm + i * 16 + q * 4 + reg;
            uint2 rm = RM[grow];
            unsigned int trow = rm.x & 255u, rsb = rm.y;
            float rs = 0.f, ms = 0.f;
            #pragma unroll
            for (int j = 0; j < 4; ++j) {
                int gcol = n0 + wn + j * 16 + lid;
                float x = acc[i][j][reg] * SC2;
                float e = exp2f(x);
                if (z == 0 && gcol == grow) e = 0.f;
                rs += e;
                if ((rmc[j].x & 255u) == trow) {
                    ms += e;
                    unsigned int slot = rsb + (rmc[j].x >> 8);
                    if (slot < LCAP) {
                        if (z == 0) {
                            Lw[slot * 4 + 0] = (unsigned)grow;
                            Lw[slot * 4 + 1] = __float_as_uint(x);
                        } else {
                            Lw[slot * 4 + 1 + z] = __float_as_uint(x);
                        }
                    }
                }
            }
            #pragma unroll
            for (int off = 1; off < 16; off <<= 1) {
                rs += __shfl_xor(rs, off);
                ms += __shfl_xor(ms, off);
            }
            if (lid == 0) {
                atomicAdd(&F[O_S + z * Bn + grow], rs);
                atomicAdd(&F[smoff + grow], ms);
            }
        }
}

// ---- flat loss pass: inline denominators, scaled atomic into d_out ----
__launch_bounds__(256)
__global__ void loss_kernel(char* ws, float* out) {
    float* F = (float*)ws;
    const unsigned int* I = (const unsigned int*)ws;
    const uint4* L = (const uint4*)(ws + LIST_OFF);
    unsigned int n = I[O_P]; if (n > LCAP) n = LCAP;
    float a0 = 0.f, a1 = 0.f;
    unsigned int stride = gridDim.x * 256;
    for (unsigned int idx = blockIdx.x * 256 + threadIdx.x; idx < n; idx += stride) {
        uint4 en = L[idx];
        int i = (int)en.x;
        float son = F[O_S + i], sgen = F[O_S + Bn + i], saug = F[O_S + 2 * Bn + i];
        float dco = (son + saug - F[O_SMOA + i]) + sgen + EPSF;
        float dad = (sgen - F[O_SMG + i]) + saug + son + DG + EPSF;
        float eo = exp2f(__uint_as_float(en.y));
        float eg = exp2f(__uint_as_float(en.z));
        float ea = exp2f(__uint_as_float(en.w));
        a0 += -__logf(eg / (eg + dad) + EPSF);
        a1 += -__logf(eo / (eo + dco) + EPSF) - __logf(ea / (ea + dco) + EPSF);
    }
    #pragma unroll
    for (int off = 1; off < 64; off <<= 1) { a0 += __shfl_xor(a0, off); a1 += __shfl_xor(a1, off); }
    __shared__ float r0[4], r1[4];
    int tid = threadIdx.x;
    if ((tid & 63) == 0) { r0[tid >> 6] = a0; r1[tid >> 6] = a1; }
    __syncthreads();
    if (tid == 0) {
        atomicAdd(&out[0], (r0[0] + r0[1] + r0[2] + r0[3]) * (1.0f / Bn));  // ad_loss
        atomicAdd(&out[1], (r1[0] + r1[1] + r1[2] + r1[3]) * (1.0f / Bn));  // co_loss
    }
}

extern "C" void kernel_launch(void* const* d_in, const int* in_sizes, int n_in,
                              void* d_out, int out_size, void* d_ws, size_t ws_size,
                              hipStream_t stream) {
    const float* f0 = (const float*)d_in[0];
    const float* f1 = (const float*)d_in[1];
    const float* f2 = (const float*)d_in[2];
    const int* tg = (const int*)d_in[3];
    char* ws = (char*)d_ws;
    unsigned int* I = (unsigned int*)d_ws;
    unsigned short* nb = (unsigned short*)(ws + NB_OFF);
    float* out = (float*)d_out;

    norm_kernel<<<dim3(Bn, 3), 256, 0, stream>>>(f0, f1, f2, nb);
    sort_kernel<<<1, 1024, 0, stream>>>(tg, I, out);
    gemm_rowsum<<<dim3(32, 32, 3), 256, 0, stream>>>(nb, ws);
    loss_kernel<<<256, 256, 0, stream>>>(ws, out);
}